// Round 6
// baseline (452.575 us; speedup 1.0000x reference)
//
#include <hip/hip_runtime.h>

typedef _Float16 f16x8 __attribute__((ext_vector_type(8)));
typedef float f32x4 __attribute__((ext_vector_type(4)));
typedef unsigned short u16;
typedef unsigned short u16x8 __attribute__((ext_vector_type(8)));

__device__ __forceinline__ u16 f2h(float f) {
  union { _Float16 h; u16 u; } v; v.h = (_Float16)f; return v.u;
}
__device__ __forceinline__ float h2f(u16 u) {
  union { _Float16 h; u16 u; } v; v.u = u; return (float)v.h;
}

// async global -> LDS, 16 B per lane, wave-uniform LDS base (+lane*16 by HW)
__device__ __forceinline__ void gload16(const u16* g, u16* l) {
  __builtin_amdgcn_global_load_lds((const __attribute__((address_space(1))) unsigned*)g,
                                   (__attribute__((address_space(3))) unsigned*)l, 16, 0, 0);
}

// ---------------- zero rowsum ----------------
__global__ void zero_k(float* __restrict__ p) {
  p[blockIdx.x * 256 + threadIdx.x] = 0.f;
}

// ---------------- cast 4 weight matrices (512x512 each) to fp16 ----------------
__global__ void cast4_k(const float* __restrict__ a0, const float* __restrict__ a1,
                        const float* __restrict__ a2, const float* __restrict__ a3,
                        u16* __restrict__ o) {
  const float* src = blockIdx.y == 0 ? a0 : blockIdx.y == 1 ? a1 : blockIdx.y == 2 ? a2 : a3;
  int i = blockIdx.x * 256 + threadIdx.x;
  o[(size_t)blockIdx.y * 262144 + i] = f2h(src[i]);
}

// ---------------- GroupNorm: x (b,c,hw) fp32 -> xn_t (b,hw,c) fp16 ----------------
__global__ void gn_k(const float* __restrict__ x, const float* __restrict__ g_,
                     const float* __restrict__ b_, u16* __restrict__ xnt) {
  const int g = blockIdx.x, b = blockIdx.y;
  const float* xb = x + ((size_t)b * 512 + g * 16) * 4096;
  u16* ob = xnt + (size_t)b * 4096 * 512 + g * 16;
  const float4* x4 = (const float4*)xb;
  float s = 0.f, ss = 0.f;
  for (int i = threadIdx.x; i < 16384; i += 256) {
    float4 v = x4[i];
    s += v.x + v.y + v.z + v.w;
    ss += v.x * v.x + v.y * v.y + v.z * v.z + v.w * v.w;
  }
  #pragma unroll
  for (int o = 32; o; o >>= 1) { s += __shfl_down(s, o); ss += __shfl_down(ss, o); }
  __shared__ float rs[4], rss[4];
  if ((threadIdx.x & 63) == 0) { rs[threadIdx.x >> 6] = s; rss[threadIdx.x >> 6] = ss; }
  __syncthreads();
  s = rs[0] + rs[1] + rs[2] + rs[3];
  ss = rss[0] + rss[1] + rss[2] + rss[3];
  const float mean = s * (1.f / 65536.f);
  const float rstd = rsqrtf(ss * (1.f / 65536.f) - mean * mean + 1e-6f);
  __shared__ float tile[16 * 257];
  const int cc_w = threadIdx.x & 15;
  const float gam = g_[g * 16 + cc_w] * rstd;
  const float bet = b_[g * 16 + cc_w] - mean * gam;
  for (int s0 = 0; s0 < 4096; s0 += 256) {
    __syncthreads();
    #pragma unroll
    for (int cc = 0; cc < 16; ++cc)
      tile[cc * 257 + threadIdx.x] = xb[(size_t)cc * 4096 + s0 + threadIdx.x];
    __syncthreads();
    #pragma unroll
    for (int it = 0; it < 16; ++it) {
      int sl = it * 16 + (threadIdx.x >> 4);
      float v = tile[cc_w * 257 + sl] * gam + bet;
      ob[(size_t)(s0 + sl) * 512 + cc_w] = f2h(v);
    }
  }
}

// ---------------- small fp16 MFMA GEMM (m97 structure), modes 4/5 ----------------
// MODE 4: C fp16 = D (m-major)                    [V' = Wo.V]
// MODE 5: QKV: z = proj*4+batch; q,k,v -> n-major fp16 +bias
template<int MODE, int BM, int BN>
__global__ void gemm_k(const u16* __restrict__ A, int lda, long long sAz,
                       const u16* __restrict__ B, int ldb, long long sBz,
                       void* __restrict__ Cp_, int ldc, long long sCz,
                       int K,
                       u16* __restrict__ Cq, u16* __restrict__ Ck, u16* __restrict__ Cvv,
                       const float* __restrict__ bq, const float* __restrict__ bk,
                       const float* __restrict__ bvp) {
  // chunked XCD swizzle (T1)
  const unsigned gx = gridDim.x, gy = gridDim.y;
  const unsigned lin = (blockIdx.z * gy + blockIdx.y) * gx + blockIdx.x;
  const unsigned nwg = gx * gy * gridDim.z;
  const unsigned swz = (lin & 7) * (nwg >> 3) + (lin >> 3);
  const unsigned bx = swz % gx;
  const unsigned rem = swz / gx;
  const unsigned by = rem % gy;
  const unsigned bz = rem / gy;

  constexpr int LK = 64;  // linear — required by global_load_lds
  __shared__ u16 As[BM * LK];
  __shared__ u16 Bs[BN * LK];
  const int tid = threadIdx.x;
  const int m0 = by * BM;
  const int n0 = bx * BN;

  const u16* Ab;
  const u16* Bb;
  if constexpr (MODE == 5) {
    int proj = bz >> 2, b = bz & 3;
    Ab = A + (size_t)proj * 512 * 512;
    Bb = B + (size_t)b * 4096 * 512;
  } else {
    Ab = A + (size_t)bz * sAz;
    Bb = B + (size_t)bz * sBz;
  }

  constexpr int FM = BM / 32, FN = BN / 32;
  f32x4 acc[FM][FN];
  #pragma unroll
  for (int i = 0; i < FM; ++i)
    #pragma unroll
    for (int j = 0; j < FN; ++j)
      acc[i][j] = (f32x4){0.f, 0.f, 0.f, 0.f};

  const int wid = tid >> 6;
  const int lane = tid & 63;
  const int wm = (wid >> 1) * (BM / 2);
  const int wn = (wid & 1) * (BN / 2);
  const int l15 = lane & 15;
  const int lk8 = (lane >> 4) * 8;
  const int lrow = lane >> 3;
  const int lcol = (lane & 7) * 8;

  constexpr int ACH = BM / 8;
  constexpr int BCH = BN / 8;

  for (int k0 = 0; k0 < K; k0 += 64) {
    #pragma unroll
    for (int c = 0; c < ACH / 4; ++c) {
      int ch = wid * (ACH / 4) + c;
      gload16(Ab + (size_t)(m0 + ch * 8 + lrow) * lda + k0 + lcol, &As[ch * 512]);
    }
    #pragma unroll
    for (int c = 0; c < BCH / 4; ++c) {
      int ch = wid * (BCH / 4) + c;
      gload16(Bb + (size_t)(n0 + ch * 8 + lrow) * ldb + k0 + lcol, &Bs[ch * 512]);
    }
    __syncthreads();
    #pragma unroll
    for (int kk = 0; kk < 64; kk += 32) {
      f16x8 af[FM], bfr[FN];
      #pragma unroll
      for (int i = 0; i < FM; ++i)
        af[i] = *(const f16x8*)&As[(wm + i * 16 + l15) * LK + kk + lk8];
      #pragma unroll
      for (int j = 0; j < FN; ++j)
        bfr[j] = *(const f16x8*)&Bs[(wn + j * 16 + l15) * LK + kk + lk8];
      #pragma unroll
      for (int i = 0; i < FM; ++i)
        #pragma unroll
        for (int j = 0; j < FN; ++j)
          acc[i][j] = __builtin_amdgcn_mfma_f32_16x16x32_f16(af[i], bfr[j], acc[i][j], 0, 0, 0);
    }
    __syncthreads();
  }

  const int lq4 = (lane >> 4) * 4;
  if constexpr (MODE == 5) {
    int proj = bz >> 2, b = bz & 3;
    const float* bs = proj == 0 ? bq : (proj == 1 ? bk : bvp);
    u16* C = (proj == 0 ? Cq : (proj == 1 ? Ck : Cvv)) + (size_t)b * 4096 * 512;
    #pragma unroll
    for (int i = 0; i < FM; ++i) {
      int mb = m0 + wm + i * 16 + lq4;
      float b0 = bs[mb], b1 = bs[mb + 1], b2 = bs[mb + 2], b3 = bs[mb + 3];
      #pragma unroll
      for (int j = 0; j < FN; ++j) {
        int n = n0 + wn + j * 16 + l15;
        ushort4 o4;
        o4.x = f2h(acc[i][j][0] + b0); o4.y = f2h(acc[i][j][1] + b1);
        o4.z = f2h(acc[i][j][2] + b2); o4.w = f2h(acc[i][j][3] + b3);
        *(ushort4*)(C + (size_t)n * 512 + mb) = o4;  // n-major
      }
    }
    return;
  }
  // MODE 4: fp16 m-major
  u16* C = (u16*)Cp_ + (size_t)bz * sCz;
  #pragma unroll
  for (int i = 0; i < FM; ++i) {
    int mb = m0 + wm + i * 16 + lq4;
    #pragma unroll
    for (int j = 0; j < FN; ++j) {
      int n = n0 + wn + j * 16 + l15;
      #pragma unroll
      for (int r = 0; r < 4; ++r)
        C[(size_t)(mb + r) * ldc + n] = f2h(acc[i][j][r]);
    }
  }
}

// ---------------- pipelined big GEMM: counted vmcnt + T2 swizzle + T5 setprio ----------------
// 512 threads = 8 waves (2M x 4N). BK=64, LDS double-buffered.
// EPI 0: expS fusion: C fp16 = exp(D*scale), rowsum[m] += row sums (atomic)   [scores]
// EPI 1: C fp32 = D / rowsum[n] + bias[m] + resid (m-major)   [out = V'.P^T norm + bo + x]
// Both epilogues transpose-stage through LDS for fully-coalesced 16B/lane stores.
template<int BM, int BN, int EPI>
__global__ __launch_bounds__(512, 2)
void gemm8_k(const u16* __restrict__ A, int lda, long long sAz,
             const u16* __restrict__ B, int ldb, long long sBz,
             void* __restrict__ Cp_, int ldc, long long sCz,
             int K,
             const float* __restrict__ bias,
             const float* __restrict__ resid, long long sRz,
             float scale, float* __restrict__ rowsum) {
  // chunked XCD swizzle (T1); all grids are %8==0
  const unsigned gx = gridDim.x, gy = gridDim.y;
  const unsigned lin = (blockIdx.z * gy + blockIdx.y) * gx + blockIdx.x;
  const unsigned nwg = gx * gy * gridDim.z;
  const unsigned swzb = (lin & 7) * (nwg >> 3) + (lin >> 3);
  const unsigned bx = swzb % gx;
  const unsigned rem = swzb / gx;
  const unsigned by = rem % gy;
  const unsigned bz = rem / gy;

  constexpr int ACH = BM / 64;        // gload16 issues per thread for A per K-tile
  constexpr int BCH = BN / 64;
  constexpr int NLD = ACH + BCH;      // loads in flight per staged K-tile
  constexpr int HBUF = (BM + BN) * 64;  // u16 per K-tile buffer
  constexpr int EPIN = EPI == 1 ? BM * BN * 2 : BM * BN;  // u16 units for epilogue tile
  constexpr int LDSN = 2 * HBUF > EPIN ? 2 * HBUF : EPIN;
  __shared__ u16 lds[LDSN];

  const int tid = threadIdx.x;
  const int m0 = by * BM;
  const int n0 = bx * BN;
  const u16* Ab = A + (size_t)bz * sAz + (size_t)m0 * lda;
  const u16* Bb = B + (size_t)bz * sBz + (size_t)n0 * ldb;

  // per-thread staging offsets (inverse-swizzled global source, linear LDS dest)
  int offA[ACH], offB[BCH];
  #pragma unroll
  for (int i = 0; i < ACH; ++i) {
    int ch = i * 512 + tid;
    int row = ch >> 3;
    int c16 = (ch & 7) ^ (row & 7);
    offA[i] = row * lda + c16 * 8;
  }
  #pragma unroll
  for (int i = 0; i < BCH; ++i) {
    int ch = i * 512 + tid;
    int row = ch >> 3;
    int c16 = (ch & 7) ^ (row & 7);
    offB[i] = row * ldb + c16 * 8;
  }

  const int wid = tid >> 6;
  const int lane = tid & 63;
  const int wm = (wid >> 2) * (BM / 2);   // 2 M-wave-rows
  const int wn = (wid & 3) * (BN / 4);    // 4 N-wave-cols
  const int l15 = lane & 15;
  const int lk8 = (lane >> 4) * 8;

  constexpr int FM = BM / 32;   // m-frags per wave
  constexpr int FN = BN / 64;   // n-frags per wave
  f32x4 acc[FM][FN];
  #pragma unroll
  for (int i = 0; i < FM; ++i)
    #pragma unroll
    for (int j = 0; j < FN; ++j)
      acc[i][j] = (f32x4){0.f, 0.f, 0.f, 0.f};

  const int NT = K >> 6;

  auto stage = [&](int t) {
    u16* dst = &lds[(t & 1) * HBUF];
    const u16* as = Ab + t * 64;
    #pragma unroll
    for (int i = 0; i < ACH; ++i)
      gload16(as + offA[i], dst + (i * 512 + tid) * 8);
    const u16* bs = Bb + t * 64;
    u16* dstB = dst + BM * 64;
    #pragma unroll
    for (int i = 0; i < BCH; ++i)
      gload16(bs + offB[i], dstB + (i * 512 + tid) * 8);
  };

  stage(0);
  stage(1);

  for (int t = 0; t < NT; ++t) {
    if (t < NT - 1)
      asm volatile("s_waitcnt vmcnt(%0)" :: "i"(NLD) : "memory");
    else
      asm volatile("s_waitcnt vmcnt(0)" ::: "memory");
    __builtin_amdgcn_s_barrier();
    __builtin_amdgcn_sched_barrier(0);

    const u16* Asp = &lds[(t & 1) * HBUF];
    const u16* Bsp = Asp + BM * 64;

    f16x8 bf[2][FN];
    #pragma unroll
    for (int k2 = 0; k2 < 2; ++k2)
      #pragma unroll
      for (int j = 0; j < FN; ++j) {
        int row = wn + j * 16 + l15;
        int col = (k2 * 32 + lk8) ^ ((row & 7) << 3);
        bf[k2][j] = *(const f16x8*)&Bsp[row * 64 + col];
      }
    #pragma unroll
    for (int q = 0; q < FM / 2; ++q) {
      f16x8 af[2][2];
      #pragma unroll
      for (int k2 = 0; k2 < 2; ++k2)
        #pragma unroll
        for (int s = 0; s < 2; ++s) {
          int row = wm + (2 * q + s) * 16 + l15;
          int col = (k2 * 32 + lk8) ^ ((row & 7) << 3);
          af[k2][s] = *(const f16x8*)&Asp[row * 64 + col];
        }
      __builtin_amdgcn_s_setprio(1);
      #pragma unroll
      for (int k2 = 0; k2 < 2; ++k2)
        #pragma unroll
        for (int s = 0; s < 2; ++s)
          #pragma unroll
          for (int j = 0; j < FN; ++j)
            acc[2 * q + s][j] =
                __builtin_amdgcn_mfma_f32_16x16x32_f16(af[k2][s], bf[k2][j], acc[2 * q + s][j], 0, 0, 0);
      __builtin_amdgcn_s_setprio(0);
    }

    asm volatile("s_waitcnt lgkmcnt(0)" ::: "memory");
    __builtin_amdgcn_sched_barrier(0);
    __builtin_amdgcn_s_barrier();
    if (t + 2 < NT) stage(t + 2);
  }

  const int lq4 = (lane >> 4) * 4;

  if constexpr (EPI == 0) {
    // exp + rowsum + LDS-transposed coalesced store of expS (fp16)
    constexpr float L2E = 1.44269504088896f;
    #pragma unroll
    for (int i = 0; i < FM; ++i) {
      #pragma unroll
      for (int j = 0; j < FN; ++j)
        #pragma unroll
        for (int r = 0; r < 4; ++r)
          acc[i][j][r] = fminf(__builtin_amdgcn_exp2f(acc[i][j][r] * (scale * L2E)), 60000.f);
      // rowsum: sum over j-frags then butterfly over the 16 col-lanes
      f32x4 rs = acc[i][0];
      #pragma unroll
      for (int j = 1; j < FN; ++j) rs += acc[i][j];
      #pragma unroll
      for (int off = 1; off < 16; off <<= 1) {
        f32x4 o;
        #pragma unroll
        for (int r = 0; r < 4; ++r) o[r] = __shfl_xor(rs[r], off);
        rs += o;
      }
      if (l15 == 0) {
        int mb = m0 + wm + i * 16 + lq4;
        #pragma unroll
        for (int r = 0; r < 4; ++r)
          atomicAdd(&rowsum[(size_t)bz * 4096 + mb + r], rs[r]);
      }
      // stage to LDS tile [BM][BN] fp16
      #pragma unroll
      for (int j = 0; j < FN; ++j) {
        int cc = wn + j * 16 + l15;
        #pragma unroll
        for (int r = 0; r < 4; ++r)
          lds[(wm + i * 16 + lq4 + r) * BN + cc] = f2h(acc[i][j][r]);
      }
    }
    __syncthreads();
    u16* Sg = (u16*)Cp_ + (size_t)bz * sCz;
    const int col = (tid * 8) & (BN - 1);
    const int rw0 = (tid * 8) / BN;
    constexpr int RPS = 512 * 8 / BN;  // rows per sweep
    #pragma unroll
    for (int s = 0; s < BM / RPS; ++s) {
      int row = s * RPS + rw0;
      *(u16x8*)(Sg + (size_t)(m0 + row) * ldc + n0 + col) =
          *(const u16x8*)&lds[row * BN + col];
    }
  } else {
    // normalize by rowsum[n], +bias[m], +resid, LDS-transposed coalesced fp32 store
    float* tf = (float*)lds;
    #pragma unroll
    for (int i = 0; i < FM; ++i)
      #pragma unroll
      for (int j = 0; j < FN; ++j) {
        int cc = wn + j * 16 + l15;
        #pragma unroll
        for (int r = 0; r < 4; ++r)
          tf[(wm + i * 16 + lq4 + r) * BN + cc] = acc[i][j][r];
      }
    __syncthreads();
    float* C = (float*)Cp_ + (size_t)bz * sCz;
    const float* R = resid + (size_t)bz * sRz;
    const int col = (tid * 4) & (BN - 1);
    const int rw0 = (tid * 4) / BN;
    constexpr int RPS = 512 * 4 / BN;  // rows per sweep
    float4 rv = *(const float4*)&rowsum[(size_t)bz * 4096 + n0 + col];
    float4 ri;
    ri.x = 1.f / rv.x; ri.y = 1.f / rv.y; ri.z = 1.f / rv.z; ri.w = 1.f / rv.w;
    #pragma unroll
    for (int s = 0; s < BM / RPS; ++s) {
      int row = s * RPS + rw0;
      float b = bias[m0 + row];
      float4 v = *(const float4*)&tf[row * BN + col];
      float4 xr = *(const float4*)(R + (size_t)(m0 + row) * ldc + n0 + col);
      v.x = v.x * ri.x + b + xr.x;
      v.y = v.y * ri.y + b + xr.y;
      v.z = v.z * ri.z + b + xr.z;
      v.w = v.w * ri.w + b + xr.w;
      *(float4*)(C + (size_t)(m0 + row) * ldc + n0 + col) = v;
    }
  }
}

extern "C" void kernel_launch(void* const* d_in, const int* in_sizes, int n_in,
                              void* d_out, int out_size, void* d_ws, size_t ws_size,
                              hipStream_t stream) {
  const float* x     = (const float*)d_in[0];
  const float* gamma = (const float*)d_in[1];
  const float* beta  = (const float*)d_in[2];
  const float* wq    = (const float*)d_in[3];
  const float* bq    = (const float*)d_in[4];
  const float* wk    = (const float*)d_in[5];
  const float* bk    = (const float*)d_in[6];
  const float* wv    = (const float*)d_in[7];
  const float* bv    = (const float*)d_in[8];
  const float* wo    = (const float*)d_in[9];
  const float* bo    = (const float*)d_in[10];
  float* out = (float*)d_out;

  const size_t BHW = (size_t)4096 * 512;       // elems per batch per tensor
  const long long SS = 16777216LL;             // 4096*4096
  u16* Wh  = (u16*)d_ws;                       // 4 x 512x512 fp16 (q,k,v,o)
  u16* xnt = Wh + (size_t)4 * 512 * 512;       // (b, s, c) — reused as V' later
  u16* qt  = xnt + 4 * BHW;                    // (b, s, c)
  u16* kt  = qt + 4 * BHW;                     // (b, s, c)
  u16* vt  = kt + 4 * BHW;                     // (b, s, c)
  u16* Sb  = vt + 4 * BHW;                     // (b, 4096, 4096) fp16 expS
  float* rowsum = (float*)(Sb + 4 * SS);       // (b, 4096) fp32
  u16* Vp  = xnt;                              // V' = Wo.V  (b, c, s) — alias, xnt dead after QKV

  const float scale = 0.044194173824159216f;   // 512^-0.5

  hipLaunchKernelGGL(zero_k, dim3(64), dim3(256), 0, stream, rowsum);
  hipLaunchKernelGGL(cast4_k, dim3(1024, 4), dim3(256), 0, stream, wq, wk, wv, wo, Wh);
  hipLaunchKernelGGL(gn_k, dim3(32, 4), dim3(256), 0, stream, x, gamma, beta, xnt);

  // QKV: M=512 (c_out), N=4096 (s), K=512; z = proj*4 + batch; all n-major out
  hipLaunchKernelGGL((gemm_k<5, 128, 128>), dim3(32, 4, 12), dim3(256), 0, stream,
                     Wh, 512, 0LL, xnt, 512, 0LL, nullptr, 0, 0LL, 512,
                     qt, kt, vt, bq, bk, bv);

  // expS[b][i][j] = exp(q_t[i][:].k_t[j][:]*scale); rowsum[b][i] += ... ; M=N=4096, K=512
  hipLaunchKernelGGL((gemm8_k<256, 256, 0>), dim3(16, 16, 4), dim3(512), 0, stream,
                     qt, 512, (long long)BHW, kt, 512, (long long)BHW,
                     Sb, 4096, SS, 512, nullptr, nullptr, 0LL, scale, rowsum);

  // V'[b][co][j] = Wo[co][:].v_t[j][:] ; M=512, N=4096, K=512 (fuses final proj)
  hipLaunchKernelGGL((gemm_k<4, 128, 128>), dim3(32, 4, 4), dim3(256), 0, stream,
                     Wh + (size_t)3 * 512 * 512, 512, 0LL, vt, 512, (long long)BHW,
                     Vp, 4096, (long long)(512 * 4096), 512,
                     nullptr, nullptr, nullptr, nullptr, nullptr, nullptr);

  // out[b][co][i] = (V'[co][:].expS[i][:]) / rowsum[i] + bo[co] + x ; M=512, N=4096, K=4096
  hipLaunchKernelGGL((gemm8_k<128, 256, 1>), dim3(16, 4, 4), dim3(512), 0, stream,
                     Vp, 4096, (long long)(512 * 4096), Sb, 4096, SS,
                     out, 4096, (long long)BHW, 4096, bo, x, (long long)BHW, 0.f, rowsum);
}

// Round 9
// 410.053 us; speedup vs baseline: 1.1037x; 1.1037x over previous
//
#include <hip/hip_runtime.h>

typedef _Float16 f16x8 __attribute__((ext_vector_type(8)));
typedef float f32x4 __attribute__((ext_vector_type(4)));
typedef unsigned short u16;
typedef unsigned short u16x8 __attribute__((ext_vector_type(8)));

__device__ __forceinline__ u16 f2h(float f) {
  union { _Float16 h; u16 u; } v; v.h = (_Float16)f; return v.u;
}
__device__ __forceinline__ float h2f(u16 u) {
  union { _Float16 h; u16 u; } v; v.u = u; return (float)v.h;
}

// async global -> LDS, 16 B per lane, wave-uniform LDS base (+lane*16 by HW)
__device__ __forceinline__ void gload16(const u16* g, u16* l) {
  __builtin_amdgcn_global_load_lds((const __attribute__((address_space(1))) unsigned*)g,
                                   (__attribute__((address_space(3))) unsigned*)l, 16, 0, 0);
}

// ---------------- rowsum reduce: rowsum[b][m] = sum over 64 slice-partials ----------------
__global__ void rsum_k(const float* __restrict__ part, float* __restrict__ rowsum) {
  int idx = blockIdx.x * 256 + threadIdx.x;   // 4*4096 total
  int bz = idx >> 12, m = idx & 4095;
  float s = 0.f;
  #pragma unroll
  for (int k = 0; k < 64; ++k)               // 16 n-blocks x 4 n-waves
    s += part[(size_t)(bz * 64 + k) * 4096 + m];
  rowsum[(size_t)bz * 4096 + m] = s;
}

// ---------------- cast 4 weight matrices (512x512 each) to fp16 ----------------
__global__ void cast4_k(const float* __restrict__ a0, const float* __restrict__ a1,
                        const float* __restrict__ a2, const float* __restrict__ a3,
                        u16* __restrict__ o) {
  const float* src = blockIdx.y == 0 ? a0 : blockIdx.y == 1 ? a1 : blockIdx.y == 2 ? a2 : a3;
  int i = blockIdx.x * 256 + threadIdx.x;
  o[(size_t)blockIdx.y * 262144 + i] = f2h(src[i]);
}

// ---------------- GroupNorm: x (b,c,hw) fp32 -> xn_t (b,hw,c) fp16 ----------------
__global__ void gn_k(const float* __restrict__ x, const float* __restrict__ g_,
                     const float* __restrict__ b_, u16* __restrict__ xnt) {
  const int g = blockIdx.x, b = blockIdx.y;
  const float* xb = x + ((size_t)b * 512 + g * 16) * 4096;
  u16* ob = xnt + (size_t)b * 4096 * 512 + g * 16;
  const float4* x4 = (const float4*)xb;
  float s = 0.f, ss = 0.f;
  for (int i = threadIdx.x; i < 16384; i += 256) {
    float4 v = x4[i];
    s += v.x + v.y + v.z + v.w;
    ss += v.x * v.x + v.y * v.y + v.z * v.z + v.w * v.w;
  }
  #pragma unroll
  for (int o = 32; o; o >>= 1) { s += __shfl_down(s, o); ss += __shfl_down(ss, o); }
  __shared__ float rs[4], rss[4];
  if ((threadIdx.x & 63) == 0) { rs[threadIdx.x >> 6] = s; rss[threadIdx.x >> 6] = ss; }
  __syncthreads();
  s = rs[0] + rs[1] + rs[2] + rs[3];
  ss = rss[0] + rss[1] + rss[2] + rss[3];
  const float mean = s * (1.f / 65536.f);
  const float rstd = rsqrtf(ss * (1.f / 65536.f) - mean * mean + 1e-6f);
  __shared__ float tile[16 * 257];
  const int cc_w = threadIdx.x & 15;
  const float gam = g_[g * 16 + cc_w] * rstd;
  const float bet = b_[g * 16 + cc_w] - mean * gam;
  for (int s0 = 0; s0 < 4096; s0 += 256) {
    __syncthreads();
    #pragma unroll
    for (int cc = 0; cc < 16; ++cc)
      tile[cc * 257 + threadIdx.x] = xb[(size_t)cc * 4096 + s0 + threadIdx.x];
    __syncthreads();
    #pragma unroll
    for (int it = 0; it < 16; ++it) {
      int sl = it * 16 + (threadIdx.x >> 4);
      float v = tile[cc_w * 257 + sl] * gam + bet;
      ob[(size_t)(s0 + sl) * 512 + cc_w] = f2h(v);
    }
  }
}

// ---------------- small fp16 MFMA GEMM (m97 structure), modes 4/5 ----------------
// MODE 4: C fp16 = D (m-major)                    [V' = Wo.V]
// MODE 5: QKV: z = proj*4+batch; q,k,v -> n-major fp16 +bias
template<int MODE, int BM, int BN>
__global__ void gemm_k(const u16* __restrict__ A, int lda, long long sAz,
                       const u16* __restrict__ B, int ldb, long long sBz,
                       void* __restrict__ Cp_, int ldc, long long sCz,
                       int K,
                       u16* __restrict__ Cq, u16* __restrict__ Ck, u16* __restrict__ Cvv,
                       const float* __restrict__ bq, const float* __restrict__ bk,
                       const float* __restrict__ bvp) {
  // chunked XCD swizzle (T1)
  const unsigned gx = gridDim.x, gy = gridDim.y;
  const unsigned lin = (blockIdx.z * gy + blockIdx.y) * gx + blockIdx.x;
  const unsigned nwg = gx * gy * gridDim.z;
  const unsigned swz = (lin & 7) * (nwg >> 3) + (lin >> 3);
  const unsigned bx = swz % gx;
  const unsigned rem = swz / gx;
  const unsigned by = rem % gy;
  const unsigned bz = rem / gy;

  constexpr int LK = 64;  // linear — required by global_load_lds
  __shared__ u16 As[BM * LK];
  __shared__ u16 Bs[BN * LK];
  const int tid = threadIdx.x;
  const int m0 = by * BM;
  const int n0 = bx * BN;

  const u16* Ab;
  const u16* Bb;
  if constexpr (MODE == 5) {
    int proj = bz >> 2, b = bz & 3;
    Ab = A + (size_t)proj * 512 * 512;
    Bb = B + (size_t)b * 4096 * 512;
  } else {
    Ab = A + (size_t)bz * sAz;
    Bb = B + (size_t)bz * sBz;
  }

  constexpr int FM = BM / 32, FN = BN / 32;
  f32x4 acc[FM][FN];
  #pragma unroll
  for (int i = 0; i < FM; ++i)
    #pragma unroll
    for (int j = 0; j < FN; ++j)
      acc[i][j] = (f32x4){0.f, 0.f, 0.f, 0.f};

  const int wid = tid >> 6;
  const int lane = tid & 63;
  const int wm = (wid >> 1) * (BM / 2);
  const int wn = (wid & 1) * (BN / 2);
  const int l15 = lane & 15;
  const int lk8 = (lane >> 4) * 8;
  const int lrow = lane >> 3;
  const int lcol = (lane & 7) * 8;

  constexpr int ACH = BM / 8;
  constexpr int BCH = BN / 8;

  for (int k0 = 0; k0 < K; k0 += 64) {
    #pragma unroll
    for (int c = 0; c < ACH / 4; ++c) {
      int ch = wid * (ACH / 4) + c;
      gload16(Ab + (size_t)(m0 + ch * 8 + lrow) * lda + k0 + lcol, &As[ch * 512]);
    }
    #pragma unroll
    for (int c = 0; c < BCH / 4; ++c) {
      int ch = wid * (BCH / 4) + c;
      gload16(Bb + (size_t)(n0 + ch * 8 + lrow) * ldb + k0 + lcol, &Bs[ch * 512]);
    }
    __syncthreads();
    #pragma unroll
    for (int kk = 0; kk < 64; kk += 32) {
      f16x8 af[FM], bfr[FN];
      #pragma unroll
      for (int i = 0; i < FM; ++i)
        af[i] = *(const f16x8*)&As[(wm + i * 16 + l15) * LK + kk + lk8];
      #pragma unroll
      for (int j = 0; j < FN; ++j)
        bfr[j] = *(const f16x8*)&Bs[(wn + j * 16 + l15) * LK + kk + lk8];
      #pragma unroll
      for (int i = 0; i < FM; ++i)
        #pragma unroll
        for (int j = 0; j < FN; ++j)
          acc[i][j] = __builtin_amdgcn_mfma_f32_16x16x32_f16(af[i], bfr[j], acc[i][j], 0, 0, 0);
    }
    __syncthreads();
  }

  const int lq4 = (lane >> 4) * 4;
  if constexpr (MODE == 5) {
    int proj = bz >> 2, b = bz & 3;
    const float* bs = proj == 0 ? bq : (proj == 1 ? bk : bvp);
    u16* C = (proj == 0 ? Cq : (proj == 1 ? Ck : Cvv)) + (size_t)b * 4096 * 512;
    #pragma unroll
    for (int i = 0; i < FM; ++i) {
      int mb = m0 + wm + i * 16 + lq4;
      float b0 = bs[mb], b1 = bs[mb + 1], b2 = bs[mb + 2], b3 = bs[mb + 3];
      #pragma unroll
      for (int j = 0; j < FN; ++j) {
        int n = n0 + wn + j * 16 + l15;
        ushort4 o4;
        o4.x = f2h(acc[i][j][0] + b0); o4.y = f2h(acc[i][j][1] + b1);
        o4.z = f2h(acc[i][j][2] + b2); o4.w = f2h(acc[i][j][3] + b3);
        *(ushort4*)(C + (size_t)n * 512 + mb) = o4;  // n-major
      }
    }
    return;
  }
  // MODE 4: fp16 m-major
  u16* C = (u16*)Cp_ + (size_t)bz * sCz;
  #pragma unroll
  for (int i = 0; i < FM; ++i) {
    int mb = m0 + wm + i * 16 + lq4;
    #pragma unroll
    for (int j = 0; j < FN; ++j) {
      int n = n0 + wn + j * 16 + l15;
      #pragma unroll
      for (int r = 0; r < 4; ++r)
        C[(size_t)(mb + r) * ldc + n] = f2h(acc[i][j][r]);
    }
  }
}

// ---------------- pipelined big GEMM: counted vmcnt + T2 swizzle + T5 setprio ----------------
// 512 threads = 8 waves (2M x 4N). BK=64, LDS double-buffered.
// EPI 0: expS fusion: C fp16 = exp(D*scale); PARTIAL rowsums -> rspart[bz][bx][wq][4096]
//        (per-N-wave slot — no atomics, no races)
// EPI 1: C fp32 = D / rowsum[n] + bias[m] + resid (m-major)
// Both epilogues transpose-stage through padded LDS for coalesced 16B/lane stores.
template<int BM, int BN, int EPI>
__global__ __launch_bounds__(512, 2)
void gemm8_k(const u16* __restrict__ A, int lda, long long sAz,
             const u16* __restrict__ B, int ldb, long long sBz,
             void* __restrict__ Cp_, int ldc, long long sCz,
             int K,
             const float* __restrict__ bias,
             const float* __restrict__ resid, long long sRz,
             float scale, float* __restrict__ rsptr) {
  // chunked XCD swizzle (T1); all grids are %8==0
  const unsigned gx = gridDim.x, gy = gridDim.y;
  const unsigned lin = (blockIdx.z * gy + blockIdx.y) * gx + blockIdx.x;
  const unsigned nwg = gx * gy * gridDim.z;
  const unsigned swzb = (lin & 7) * (nwg >> 3) + (lin >> 3);
  const unsigned bx = swzb % gx;
  const unsigned rem = swzb / gx;
  const unsigned by = rem % gy;
  const unsigned bz = rem / gy;

  constexpr int ACH = BM / 64;        // gload16 issues per thread for A per K-tile
  constexpr int BCH = BN / 64;
  constexpr int NLD = ACH + BCH;      // loads in flight per staged K-tile
  constexpr int HBUF = (BM + BN) * 64;  // u16 per K-tile buffer
  // padded epilogue tile (u16 units): EPI0 u16[BM][BN+8]; EPI1 f32[BM][BN+4]
  constexpr int EST = EPI == 0 ? BN + 8 : 2 * (BN + 4);
  constexpr int EPIN = BM * EST;
  constexpr int LDSN = 2 * HBUF > EPIN ? 2 * HBUF : EPIN;
  __shared__ u16 lds[LDSN];

  const int tid = threadIdx.x;
  const int m0 = by * BM;
  const int n0 = bx * BN;
  const u16* Ab = A + (size_t)bz * sAz + (size_t)m0 * lda;
  const u16* Bb = B + (size_t)bz * sBz + (size_t)n0 * ldb;

  // per-thread staging offsets (inverse-swizzled global source, linear LDS dest)
  int offA[ACH], offB[BCH];
  #pragma unroll
  for (int i = 0; i < ACH; ++i) {
    int ch = i * 512 + tid;
    int row = ch >> 3;
    int c16 = (ch & 7) ^ (row & 7);
    offA[i] = row * lda + c16 * 8;
  }
  #pragma unroll
  for (int i = 0; i < BCH; ++i) {
    int ch = i * 512 + tid;
    int row = ch >> 3;
    int c16 = (ch & 7) ^ (row & 7);
    offB[i] = row * ldb + c16 * 8;
  }

  const int wid = tid >> 6;
  const int lane = tid & 63;
  const int wm = (wid >> 2) * (BM / 2);   // 2 M-wave-rows
  const int wn = (wid & 3) * (BN / 4);    // 4 N-wave-cols
  const int l15 = lane & 15;
  const int lk8 = (lane >> 4) * 8;

  constexpr int FM = BM / 32;   // m-frags per wave
  constexpr int FN = BN / 64;   // n-frags per wave
  f32x4 acc[FM][FN];
  #pragma unroll
  for (int i = 0; i < FM; ++i)
    #pragma unroll
    for (int j = 0; j < FN; ++j)
      acc[i][j] = (f32x4){0.f, 0.f, 0.f, 0.f};

  const int NT = K >> 6;

  auto stage = [&](int t) {
    u16* dst = &lds[(t & 1) * HBUF];
    const u16* as = Ab + t * 64;
    #pragma unroll
    for (int i = 0; i < ACH; ++i)
      gload16(as + offA[i], dst + (i * 512 + tid) * 8);
    const u16* bs = Bb + t * 64;
    u16* dstB = dst + BM * 64;
    #pragma unroll
    for (int i = 0; i < BCH; ++i)
      gload16(bs + offB[i], dstB + (i * 512 + tid) * 8);
  };

  stage(0);
  stage(1);

  for (int t = 0; t < NT; ++t) {
    if (t < NT - 1)
      asm volatile("s_waitcnt vmcnt(%0)" :: "i"(NLD) : "memory");
    else
      asm volatile("s_waitcnt vmcnt(0)" ::: "memory");
    __builtin_amdgcn_s_barrier();
    __builtin_amdgcn_sched_barrier(0);

    const u16* Asp = &lds[(t & 1) * HBUF];
    const u16* Bsp = Asp + BM * 64;

    f16x8 bf[2][FN];
    #pragma unroll
    for (int k2 = 0; k2 < 2; ++k2)
      #pragma unroll
      for (int j = 0; j < FN; ++j) {
        int row = wn + j * 16 + l15;
        int col = (k2 * 32 + lk8) ^ ((row & 7) << 3);
        bf[k2][j] = *(const f16x8*)&Bsp[row * 64 + col];
      }
    #pragma unroll
    for (int q = 0; q < FM / 2; ++q) {
      f16x8 af[2][2];
      #pragma unroll
      for (int k2 = 0; k2 < 2; ++k2)
        #pragma unroll
        for (int s = 0; s < 2; ++s) {
          int row = wm + (2 * q + s) * 16 + l15;
          int col = (k2 * 32 + lk8) ^ ((row & 7) << 3);
          af[k2][s] = *(const f16x8*)&Asp[row * 64 + col];
        }
      __builtin_amdgcn_s_setprio(1);
      #pragma unroll
      for (int k2 = 0; k2 < 2; ++k2)
        #pragma unroll
        for (int s = 0; s < 2; ++s)
          #pragma unroll
          for (int j = 0; j < FN; ++j)
            acc[2 * q + s][j] =
                __builtin_amdgcn_mfma_f32_16x16x32_f16(af[k2][s], bf[k2][j], acc[2 * q + s][j], 0, 0, 0);
      __builtin_amdgcn_s_setprio(0);
    }

    asm volatile("s_waitcnt lgkmcnt(0)" ::: "memory");
    __builtin_amdgcn_sched_barrier(0);
    __builtin_amdgcn_s_barrier();
    if (t + 2 < NT) stage(t + 2);
  }

  const int lq4 = (lane >> 4) * 4;

  if constexpr (EPI == 0) {
    // exp + per-N-wave partial rowsum (plain stores, race-free) + padded-LDS coalesced store
    constexpr float L2E = 1.44269504088896f;
    // slot = (bz*gx + bx)*4 + N-wave-id  -> each wave owns its 64-col slice partial
    float* part = rsptr + ((size_t)(bz * gx + bx) * 4 + (wid & 3)) * 4096;
    #pragma unroll
    for (int i = 0; i < FM; ++i) {
      #pragma unroll
      for (int j = 0; j < FN; ++j)
        #pragma unroll
        for (int r = 0; r < 4; ++r)
          acc[i][j][r] = fminf(__builtin_amdgcn_exp2f(acc[i][j][r] * (scale * L2E)), 60000.f);
      // rowsum partial: sum over this wave's j-frags then butterfly over the 16 col-lanes
      f32x4 rs = acc[i][0];
      #pragma unroll
      for (int j = 1; j < FN; ++j) rs += acc[i][j];
      #pragma unroll
      for (int off = 1; off < 16; off <<= 1) {
        f32x4 o;
        #pragma unroll
        for (int r = 0; r < 4; ++r) o[r] = __shfl_xor(rs[r], off);
        rs += o;
      }
      if (l15 == 0) {
        int mb = m0 + wm + i * 16 + lq4;
        float4 st; st.x = rs[0]; st.y = rs[1]; st.z = rs[2]; st.w = rs[3];
        *(float4*)&part[mb] = st;
      }
      // stage to padded LDS tile [BM][BN+8] fp16
      #pragma unroll
      for (int j = 0; j < FN; ++j) {
        int cc = wn + j * 16 + l15;
        #pragma unroll
        for (int r = 0; r < 4; ++r)
          lds[(wm + i * 16 + lq4 + r) * EST + cc] = f2h(acc[i][j][r]);
      }
    }
    __syncthreads();
    u16* Sg = (u16*)Cp_ + (size_t)bz * sCz;
    const int col = (tid * 8) & (BN - 1);
    const int rw0 = (tid * 8) / BN;
    constexpr int RPS = 512 * 8 / BN;  // rows per sweep
    #pragma unroll
    for (int s = 0; s < BM / RPS; ++s) {
      int row = s * RPS + rw0;
      *(u16x8*)(Sg + (size_t)(m0 + row) * ldc + n0 + col) =
          *(const u16x8*)&lds[row * EST + col];
    }
  } else {
    // normalize by rowsum[n], +bias[m], +resid, padded-LDS coalesced fp32 store
    constexpr int FST = BN + 4;  // float stride
    float* tf = (float*)lds;
    #pragma unroll
    for (int i = 0; i < FM; ++i)
      #pragma unroll
      for (int j = 0; j < FN; ++j) {
        int cc = wn + j * 16 + l15;
        #pragma unroll
        for (int r = 0; r < 4; ++r)
          tf[(wm + i * 16 + lq4 + r) * FST + cc] = acc[i][j][r];
      }
    __syncthreads();
    float* C = (float*)Cp_ + (size_t)bz * sCz;
    const float* R = resid + (size_t)bz * sRz;
    const int col = (tid * 4) & (BN - 1);
    const int rw0 = (tid * 4) / BN;
    constexpr int RPS = 512 * 4 / BN;  // rows per sweep
    float4 rv = *(const float4*)&rsptr[(size_t)bz * 4096 + n0 + col];
    float4 ri;
    ri.x = 1.f / rv.x; ri.y = 1.f / rv.y; ri.z = 1.f / rv.z; ri.w = 1.f / rv.w;
    #pragma unroll
    for (int s = 0; s < BM / RPS; ++s) {
      int row = s * RPS + rw0;
      float b = bias[m0 + row];
      float4 v = *(const float4*)&tf[row * FST + col];
      float4 xr = *(const float4*)(R + (size_t)(m0 + row) * ldc + n0 + col);
      v.x = v.x * ri.x + b + xr.x;
      v.y = v.y * ri.y + b + xr.y;
      v.z = v.z * ri.z + b + xr.z;
      v.w = v.w * ri.w + b + xr.w;
      *(float4*)(C + (size_t)(m0 + row) * ldc + n0 + col) = v;
    }
  }
}

extern "C" void kernel_launch(void* const* d_in, const int* in_sizes, int n_in,
                              void* d_out, int out_size, void* d_ws, size_t ws_size,
                              hipStream_t stream) {
  const float* x     = (const float*)d_in[0];
  const float* gamma = (const float*)d_in[1];
  const float* beta  = (const float*)d_in[2];
  const float* wq    = (const float*)d_in[3];
  const float* bq    = (const float*)d_in[4];
  const float* wk    = (const float*)d_in[5];
  const float* bk    = (const float*)d_in[6];
  const float* wv    = (const float*)d_in[7];
  const float* bv    = (const float*)d_in[8];
  const float* wo    = (const float*)d_in[9];
  const float* bo    = (const float*)d_in[10];
  float* out = (float*)d_out;

  const size_t BHW = (size_t)4096 * 512;       // elems per batch per tensor
  const long long SS = 16777216LL;             // 4096*4096
  u16* Wh  = (u16*)d_ws;                       // 4 x 512x512 fp16 (q,k,v,o)
  u16* xnt = Wh + (size_t)4 * 512 * 512;       // (b, s, c) — reused as V' later
  u16* qt  = xnt + 4 * BHW;                    // (b, s, c)
  u16* kt  = qt + 4 * BHW;                     // (b, s, c)
  u16* vt  = kt + 4 * BHW;                     // (b, s, c)
  u16* Sb  = vt + 4 * BHW;                     // (b, 4096, 4096) fp16 expS
  float* rowsum = (float*)(Sb + 4 * SS);       // (b, 4096) fp32
  float* rspart = rowsum + 4 * 4096;           // (b, 16, 4, 4096) fp32 slice partials
  u16* Vp  = xnt;                              // V' = Wo.V  (b, c, s) — alias, xnt dead after QKV

  const float scale = 0.044194173824159216f;   // 512^-0.5

  hipLaunchKernelGGL(cast4_k, dim3(1024, 4), dim3(256), 0, stream, wq, wk, wv, wo, Wh);
  hipLaunchKernelGGL(gn_k, dim3(32, 4), dim3(256), 0, stream, x, gamma, beta, xnt);

  // QKV: M=512 (c_out), N=4096 (s), K=512; z = proj*4 + batch; all n-major out
  hipLaunchKernelGGL((gemm_k<5, 128, 128>), dim3(32, 4, 12), dim3(256), 0, stream,
                     Wh, 512, 0LL, xnt, 512, 0LL, nullptr, 0, 0LL, 512,
                     qt, kt, vt, bq, bk, bv);

  // expS[b][i][j] = exp(q.k*scale); slice partial rowsums -> rspart ; M=N=4096, K=512
  hipLaunchKernelGGL((gemm8_k<256, 256, 0>), dim3(16, 16, 4), dim3(512), 0, stream,
                     qt, 512, (long long)BHW, kt, 512, (long long)BHW,
                     Sb, 4096, SS, 512, nullptr, nullptr, 0LL, scale, rspart);

  // rowsum[b][m] = sum over 64 slice partials
  hipLaunchKernelGGL(rsum_k, dim3(64), dim3(256), 0, stream, rspart, rowsum);

  // V'[b][co][j] = Wo[co][:].v_t[j][:] ; M=512, N=4096, K=512 (fuses final proj)
  hipLaunchKernelGGL((gemm_k<4, 128, 128>), dim3(32, 4, 4), dim3(256), 0, stream,
                     Wh + (size_t)3 * 512 * 512, 512, 0LL, vt, 512, (long long)BHW,
                     Vp, 4096, (long long)(512 * 4096), 512,
                     nullptr, nullptr, nullptr, nullptr, nullptr, nullptr);

  // out[b][co][i] = (V'[co][:].expS[i][:]) / rowsum[i] + bo[co] + x ; M=512, N=4096, K=4096
  hipLaunchKernelGGL((gemm8_k<128, 256, 1>), dim3(16, 4, 4), dim3(512), 0, stream,
                     Vp, 4096, (long long)(512 * 4096), Sb, 4096, SS,
                     out, 4096, (long long)BHW, 4096, bo, x, (long long)BHW, 0.f, rowsum);
}

// Round 11
// 397.228 us; speedup vs baseline: 1.1393x; 1.0323x over previous
//
#include <hip/hip_runtime.h>

typedef _Float16 f16x8 __attribute__((ext_vector_type(8)));
typedef float f32x4 __attribute__((ext_vector_type(4)));
typedef unsigned short u16;
typedef unsigned short u16x8 __attribute__((ext_vector_type(8)));

__device__ __forceinline__ u16 f2h(float f) {
  union { _Float16 h; u16 u; } v; v.h = (_Float16)f; return v.u;
}

// async global -> LDS, 16 B per lane, wave-uniform LDS base (+lane*16 by HW)
__device__ __forceinline__ void gload16(const u16* g, u16* l) {
  __builtin_amdgcn_global_load_lds((const __attribute__((address_space(1))) unsigned*)g,
                                   (__attribute__((address_space(3))) unsigned*)l, 16, 0, 0);
}

// ---------------- rowsum reduce: rowsum[b][m] = sum over 64 slice-partials ----------------
__global__ void rsum_k(const float* __restrict__ part, float* __restrict__ rowsum) {
  int idx = blockIdx.x * 256 + threadIdx.x;   // 4*4096 total
  int bz = idx >> 12, m = idx & 4095;
  float s = 0.f;
  #pragma unroll
  for (int k = 0; k < 64; ++k)               // 16 n-blocks x 4 n-waves
    s += part[(size_t)(bz * 64 + k) * 4096 + m];
  rowsum[(size_t)bz * 4096 + m] = s;
}

// ---------------- cast 4 weight matrices (512x512 each) to fp16 ----------------
__global__ void cast4_k(const float* __restrict__ a0, const float* __restrict__ a1,
                        const float* __restrict__ a2, const float* __restrict__ a3,
                        u16* __restrict__ o) {
  const float* src = blockIdx.y == 0 ? a0 : blockIdx.y == 1 ? a1 : blockIdx.y == 2 ? a2 : a3;
  int i = blockIdx.x * 256 + threadIdx.x;
  o[(size_t)blockIdx.y * 262144 + i] = f2h(src[i]);
}

// ---------------- GroupNorm stats: mean/rstd per (b,g) ----------------
__global__ void gnstat_k(const float* __restrict__ x, float* __restrict__ st) {
  const int g = blockIdx.x, b = blockIdx.y;
  const float4* x4 = (const float4*)(x + ((size_t)b * 512 + g * 16) * 4096);
  float s = 0.f, ss = 0.f;
  for (int i = threadIdx.x; i < 16384; i += 256) {
    float4 v = x4[i];
    s += v.x + v.y + v.z + v.w;
    ss += v.x * v.x + v.y * v.y + v.z * v.z + v.w * v.w;
  }
  #pragma unroll
  for (int o = 32; o; o >>= 1) { s += __shfl_down(s, o); ss += __shfl_down(ss, o); }
  __shared__ float rs[4], rss[4];
  if ((threadIdx.x & 63) == 0) { rs[threadIdx.x >> 6] = s; rss[threadIdx.x >> 6] = ss; }
  __syncthreads();
  if (threadIdx.x == 0) {
    s = rs[0] + rs[1] + rs[2] + rs[3];
    ss = rss[0] + rss[1] + rss[2] + rss[3];
    const float mean = s * (1.f / 65536.f);
    const float rstd = rsqrtf(ss * (1.f / 65536.f) - mean * mean + 1e-6f);
    st[(b * 32 + g) * 2] = mean;
    st[(b * 32 + g) * 2 + 1] = rstd;
  }
}

// ---------------- GroupNorm apply: x -> xn_t (b,hw,c) fp16; grid (32,4,8) ----------------
__global__ void gnapply_k(const float* __restrict__ x, const float* __restrict__ g_,
                          const float* __restrict__ b_, const float* __restrict__ st,
                          u16* __restrict__ xnt) {
  const int g = blockIdx.x, b = blockIdx.y, sc = blockIdx.z;
  const float* xb = x + ((size_t)b * 512 + g * 16) * 4096;
  u16* ob = xnt + (size_t)b * 4096 * 512 + g * 16;
  const float mean = st[(b * 32 + g) * 2];
  const float rstd = st[(b * 32 + g) * 2 + 1];
  __shared__ float tile[16 * 257];
  const int cc_w = threadIdx.x & 15;
  const float gam = g_[g * 16 + cc_w] * rstd;
  const float bet = b_[g * 16 + cc_w] - mean * gam;
  for (int s0 = sc * 512; s0 < sc * 512 + 512; s0 += 256) {
    __syncthreads();
    #pragma unroll
    for (int cc = 0; cc < 16; ++cc)
      tile[cc * 257 + threadIdx.x] = xb[(size_t)cc * 4096 + s0 + threadIdx.x];
    __syncthreads();
    #pragma unroll
    for (int it = 0; it < 16; ++it) {
      int sl = it * 16 + (threadIdx.x >> 4);
      float v = tile[cc_w * 257 + sl] * gam + bet;
      ob[(size_t)(s0 + sl) * 512 + cc_w] = f2h(v);
    }
  }
}

// ---------------- small fp16 MFMA GEMM (m97 structure), modes 4/5 ----------------
// MODE 4: C fp16 = D (m-major, ldc)               [V' = Wo.V]
// MODE 5: QKV: z = proj*4+batch; q,k,v ALL -> n-major (s,c) fp16 +bias
// All epilogues LDS-transposed for coalesced 256B-run u16x8 stores.
template<int MODE, int BM, int BN>
__global__ void gemm_k(const u16* __restrict__ A, int lda, long long sAz,
                       const u16* __restrict__ B, int ldb, long long sBz,
                       void* __restrict__ Cp_, int ldc, long long sCz,
                       int K,
                       u16* __restrict__ Cq, u16* __restrict__ Ck, u16* __restrict__ Cvv,
                       const float* __restrict__ bq, const float* __restrict__ bk,
                       const float* __restrict__ bvp) {
  // chunked XCD swizzle (T1)
  const unsigned gx = gridDim.x, gy = gridDim.y;
  const unsigned lin = (blockIdx.z * gy + blockIdx.y) * gx + blockIdx.x;
  const unsigned nwg = gx * gy * gridDim.z;
  const unsigned swz = (lin & 7) * (nwg >> 3) + (lin >> 3);
  const unsigned bx = swz % gx;
  const unsigned rem = swz / gx;
  const unsigned by = rem % gy;
  const unsigned bz = rem / gy;

  constexpr int LK = 64;  // linear — required by global_load_lds
  constexpr int STG = (BM + BN) * LK;     // staging u16
  constexpr int EPT = BN * (BM + 8) > BM * (BN + 8) ? BN * (BM + 8) : BM * (BN + 8);
  constexpr int LDSN = STG > EPT ? STG : EPT;
  __shared__ u16 sh[LDSN];
  u16* As = sh;
  u16* Bs = sh + BM * LK;
  const int tid = threadIdx.x;
  const int m0 = by * BM;
  const int n0 = bx * BN;

  const u16* Ab;
  const u16* Bb;
  if constexpr (MODE == 5) {
    int proj = bz >> 2, b = bz & 3;
    Ab = A + (size_t)proj * 512 * 512;
    Bb = B + (size_t)b * 4096 * 512;
  } else {
    Ab = A + (size_t)bz * sAz;
    Bb = B + (size_t)bz * sBz;
  }

  constexpr int FM = BM / 32, FN = BN / 32;
  f32x4 acc[FM][FN];
  #pragma unroll
  for (int i = 0; i < FM; ++i)
    #pragma unroll
    for (int j = 0; j < FN; ++j)
      acc[i][j] = (f32x4){0.f, 0.f, 0.f, 0.f};

  const int wid = tid >> 6;
  const int lane = tid & 63;
  const int wm = (wid >> 1) * (BM / 2);
  const int wn = (wid & 1) * (BN / 2);
  const int l15 = lane & 15;
  const int lk8 = (lane >> 4) * 8;
  const int lrow = lane >> 3;
  const int lcol = (lane & 7) * 8;

  constexpr int ACH = BM / 8;
  constexpr int BCH = BN / 8;

  for (int k0 = 0; k0 < K; k0 += 64) {
    #pragma unroll
    for (int c = 0; c < ACH / 4; ++c) {
      int ch = wid * (ACH / 4) + c;
      gload16(Ab + (size_t)(m0 + ch * 8 + lrow) * lda + k0 + lcol, &As[ch * 512]);
    }
    #pragma unroll
    for (int c = 0; c < BCH / 4; ++c) {
      int ch = wid * (BCH / 4) + c;
      gload16(Bb + (size_t)(n0 + ch * 8 + lrow) * ldb + k0 + lcol, &Bs[ch * 512]);
    }
    __syncthreads();
    #pragma unroll
    for (int kk = 0; kk < 64; kk += 32) {
      f16x8 af[FM], bfr[FN];
      #pragma unroll
      for (int i = 0; i < FM; ++i)
        af[i] = *(const f16x8*)&As[(wm + i * 16 + l15) * LK + kk + lk8];
      #pragma unroll
      for (int j = 0; j < FN; ++j)
        bfr[j] = *(const f16x8*)&Bs[(wn + j * 16 + l15) * LK + kk + lk8];
      #pragma unroll
      for (int i = 0; i < FM; ++i)
        #pragma unroll
        for (int j = 0; j < FN; ++j)
          acc[i][j] = __builtin_amdgcn_mfma_f32_16x16x32_f16(af[i], bfr[j], acc[i][j], 0, 0, 0);
    }
    __syncthreads();  // also guarantees LDS free for epilogue reuse
  }

  const int lq4 = (lane >> 4) * 4;
  const int er0 = tid >> 4;         // epilogue sweep row
  const int ec0 = (tid & 15) * 8;   // epilogue sweep col (u16)

  if constexpr (MODE == 5) {
    int proj = bz >> 2, b = bz & 3;
    const float* bs = proj == 0 ? bq : (proj == 1 ? bk : bvp);
    // ALL projections n-major (s,c): LDS tile T[n_l][BM+8]
    constexpr int TS = BM + 8;
    #pragma unroll
    for (int i = 0; i < FM; ++i) {
      int mbl = wm + i * 16 + lq4;
      float b0 = bs[m0 + mbl], b1 = bs[m0 + mbl + 1],
            b2 = bs[m0 + mbl + 2], b3 = bs[m0 + mbl + 3];
      #pragma unroll
      for (int j = 0; j < FN; ++j) {
        int nl = wn + j * 16 + l15;
        sh[nl * TS + mbl]     = f2h(acc[i][j][0] + b0);
        sh[nl * TS + mbl + 1] = f2h(acc[i][j][1] + b1);
        sh[nl * TS + mbl + 2] = f2h(acc[i][j][2] + b2);
        sh[nl * TS + mbl + 3] = f2h(acc[i][j][3] + b3);
      }
    }
    __syncthreads();
    u16* C = (proj == 0 ? Cq : (proj == 1 ? Ck : Cvv)) + (size_t)b * 4096 * 512;
    #pragma unroll
    for (int s = 0; s < BN / 16; ++s) {
      int row = s * 16 + er0;
      *(u16x8*)(C + (size_t)(n0 + row) * 512 + m0 + ec0) = *(const u16x8*)&sh[row * TS + ec0];
    }
    return;
  }
  // MODE 4: fp16 m-major via LDS transpose
  {
    constexpr int TS = BN + 8;
    #pragma unroll
    for (int i = 0; i < FM; ++i) {
      int mbl = wm + i * 16 + lq4;
      #pragma unroll
      for (int j = 0; j < FN; ++j) {
        int nl = wn + j * 16 + l15;
        sh[(mbl) * TS + nl]     = f2h(acc[i][j][0]);
        sh[(mbl + 1) * TS + nl] = f2h(acc[i][j][1]);
        sh[(mbl + 2) * TS + nl] = f2h(acc[i][j][2]);
        sh[(mbl + 3) * TS + nl] = f2h(acc[i][j][3]);
      }
    }
    __syncthreads();
    u16* C = (u16*)Cp_ + (size_t)bz * sCz;
    #pragma unroll
    for (int s = 0; s < BM / 16; ++s) {
      int row = s * 16 + er0;
      *(u16x8*)(C + (size_t)(m0 + row) * ldc + n0 + ec0) = *(const u16x8*)&sh[row * TS + ec0];
    }
  }
}

// ---------------- pipelined big GEMM: counted vmcnt + T2 swizzle + T5 setprio ----------------
// 512 threads = 8 waves (2M x 4N). BK=64, LDS double-buffered.
// EPI 0: expS fusion: C fp16 = exp(D*scale); PARTIAL rowsums -> rspart[bz][bx][wq][4096]
// EPI 1: C fp32 = D / rowsum[n] + bias[m] + resid; decode M-FASTEST so the 4 m-blocks
//        sharing one 2MB expS B-panel run consecutively on the same XCD (L2 reuse).
template<int BM, int BN, int EPI>
__global__ __launch_bounds__(512, 2)
void gemm8_k(const u16* __restrict__ A, int lda, long long sAz,
             const u16* __restrict__ B, int ldb, long long sBz,
             void* __restrict__ Cp_, int ldc, long long sCz,
             int K,
             const float* __restrict__ bias,
             const float* __restrict__ resid, long long sRz,
             float scale, float* __restrict__ rsptr) {
  // chunked XCD swizzle (T1); all grids are %8==0
  const unsigned gx = gridDim.x, gy = gridDim.y;
  const unsigned lin = (blockIdx.z * gy + blockIdx.y) * gx + blockIdx.x;
  const unsigned nwg = gx * gy * gridDim.z;
  const unsigned swzb = (lin & 7) * (nwg >> 3) + (lin >> 3);
  unsigned bx, by, bz;
  if constexpr (EPI == 1) {
    by = swzb % gy; unsigned r2 = swzb / gy; bx = r2 % gx; bz = r2 / gx;
  } else {
    bx = swzb % gx; unsigned r2 = swzb / gx; by = r2 % gy; bz = r2 / gy;
  }

  constexpr int ACH = BM / 64;        // gload16 issues per thread for A per K-tile
  constexpr int BCH = BN / 64;
  constexpr int NLD = ACH + BCH;      // loads in flight per staged K-tile
  constexpr int HBUF = (BM + BN) * 64;  // u16 per K-tile buffer
  // padded epilogue tile (u16 units): EPI0 u16[BM][BN+8]; EPI1 f32[BM][BN+4]
  constexpr int EST = EPI == 0 ? BN + 8 : 2 * (BN + 4);
  constexpr int EPIN = BM * EST;
  constexpr int LDSN = 2 * HBUF > EPIN ? 2 * HBUF : EPIN;
  __shared__ u16 lds[LDSN];

  const int tid = threadIdx.x;
  const int m0 = by * BM;
  const int n0 = bx * BN;
  const u16* Ab = A + (size_t)bz * sAz + (size_t)m0 * lda;
  const u16* Bb = B + (size_t)bz * sBz + (size_t)n0 * ldb;

  // per-thread staging offsets (inverse-swizzled global source, linear LDS dest)
  int offA[ACH], offB[BCH];
  #pragma unroll
  for (int i = 0; i < ACH; ++i) {
    int ch = i * 512 + tid;
    int row = ch >> 3;
    int c16 = (ch & 7) ^ (row & 7);
    offA[i] = row * lda + c16 * 8;
  }
  #pragma unroll
  for (int i = 0; i < BCH; ++i) {
    int ch = i * 512 + tid;
    int row = ch >> 3;
    int c16 = (ch & 7) ^ (row & 7);
    offB[i] = row * ldb + c16 * 8;
  }

  const int wid = tid >> 6;
  const int lane = tid & 63;
  const int wm = (wid >> 2) * (BM / 2);   // 2 M-wave-rows
  const int wn = (wid & 3) * (BN / 4);    // 4 N-wave-cols
  const int l15 = lane & 15;
  const int lk8 = (lane >> 4) * 8;

  constexpr int FM = BM / 32;   // m-frags per wave
  constexpr int FN = BN / 64;   // n-frags per wave
  f32x4 acc[FM][FN];
  #pragma unroll
  for (int i = 0; i < FM; ++i)
    #pragma unroll
    for (int j = 0; j < FN; ++j)
      acc[i][j] = (f32x4){0.f, 0.f, 0.f, 0.f};

  const int NT = K >> 6;

  auto stage = [&](int t) {
    u16* dst = &lds[(t & 1) * HBUF];
    const u16* as = Ab + t * 64;
    #pragma unroll
    for (int i = 0; i < ACH; ++i)
      gload16(as + offA[i], dst + (i * 512 + tid) * 8);
    const u16* bs = Bb + t * 64;
    u16* dstB = dst + BM * 64;
    #pragma unroll
    for (int i = 0; i < BCH; ++i)
      gload16(bs + offB[i], dstB + (i * 512 + tid) * 8);
  };

  stage(0);
  stage(1);

  for (int t = 0; t < NT; ++t) {
    if (t < NT - 1)
      asm volatile("s_waitcnt vmcnt(%0)" :: "i"(NLD) : "memory");
    else
      asm volatile("s_waitcnt vmcnt(0)" ::: "memory");
    __builtin_amdgcn_s_barrier();
    __builtin_amdgcn_sched_barrier(0);

    const u16* Asp = &lds[(t & 1) * HBUF];
    const u16* Bsp = Asp + BM * 64;

    f16x8 bf[2][FN];
    #pragma unroll
    for (int k2 = 0; k2 < 2; ++k2)
      #pragma unroll
      for (int j = 0; j < FN; ++j) {
        int row = wn + j * 16 + l15;
        int col = (k2 * 32 + lk8) ^ ((row & 7) << 3);
        bf[k2][j] = *(const f16x8*)&Bsp[row * 64 + col];
      }
    #pragma unroll
    for (int q = 0; q < FM / 2; ++q) {
      f16x8 af[2][2];
      #pragma unroll
      for (int k2 = 0; k2 < 2; ++k2)
        #pragma unroll
        for (int s = 0; s < 2; ++s) {
          int row = wm + (2 * q + s) * 16 + l15;
          int col = (k2 * 32 + lk8) ^ ((row & 7) << 3);
          af[k2][s] = *(const f16x8*)&Asp[row * 64 + col];
        }
      __builtin_amdgcn_s_setprio(1);
      #pragma unroll
      for (int k2 = 0; k2 < 2; ++k2)
        #pragma unroll
        for (int s = 0; s < 2; ++s)
          #pragma unroll
          for (int j = 0; j < FN; ++j)
            acc[2 * q + s][j] =
                __builtin_amdgcn_mfma_f32_16x16x32_f16(af[k2][s], bf[k2][j], acc[2 * q + s][j], 0, 0, 0);
      __builtin_amdgcn_s_setprio(0);
    }

    asm volatile("s_waitcnt lgkmcnt(0)" ::: "memory");
    __builtin_amdgcn_sched_barrier(0);
    __builtin_amdgcn_s_barrier();
    if (t + 2 < NT) stage(t + 2);
  }

  const int lq4 = (lane >> 4) * 4;

  if constexpr (EPI == 0) {
    // exp + per-N-wave partial rowsum (plain stores, race-free) + padded-LDS coalesced store
    constexpr float L2E = 1.44269504088896f;
    float* part = rsptr + ((size_t)(bz * gx + bx) * 4 + (wid & 3)) * 4096;
    #pragma unroll
    for (int i = 0; i < FM; ++i) {
      #pragma unroll
      for (int j = 0; j < FN; ++j)
        #pragma unroll
        for (int r = 0; r < 4; ++r)
          acc[i][j][r] = fminf(__builtin_amdgcn_exp2f(acc[i][j][r] * (scale * L2E)), 60000.f);
      f32x4 rs = acc[i][0];
      #pragma unroll
      for (int j = 1; j < FN; ++j) rs += acc[i][j];
      #pragma unroll
      for (int off = 1; off < 16; off <<= 1) {
        f32x4 o;
        #pragma unroll
        for (int r = 0; r < 4; ++r) o[r] = __shfl_xor(rs[r], off);
        rs += o;
      }
      if (l15 == 0) {
        int mb = m0 + wm + i * 16 + lq4;
        float4 st; st.x = rs[0]; st.y = rs[1]; st.z = rs[2]; st.w = rs[3];
        *(float4*)&part[mb] = st;
      }
      #pragma unroll
      for (int j = 0; j < FN; ++j) {
        int cc = wn + j * 16 + l15;
        #pragma unroll
        for (int r = 0; r < 4; ++r)
          lds[(wm + i * 16 + lq4 + r) * EST + cc] = f2h(acc[i][j][r]);
      }
    }
    __syncthreads();
    u16* Sg = (u16*)Cp_ + (size_t)bz * sCz;
    const int col = (tid * 8) & (BN - 1);
    const int rw0 = (tid * 8) / BN;
    constexpr int RPS = 512 * 8 / BN;  // rows per sweep
    #pragma unroll
    for (int s = 0; s < BM / RPS; ++s) {
      int row = s * RPS + rw0;
      *(u16x8*)(Sg + (size_t)(m0 + row) * ldc + n0 + col) =
          *(const u16x8*)&lds[row * EST + col];
    }
  } else {
    // normalize by rowsum[n], +bias[m], +resid, padded-LDS coalesced fp32 store
    constexpr int FST = BN + 4;  // float stride
    float* tf = (float*)lds;
    #pragma unroll
    for (int i = 0; i < FM; ++i)
      #pragma unroll
      for (int j = 0; j < FN; ++j) {
        int cc = wn + j * 16 + l15;
        #pragma unroll
        for (int r = 0; r < 4; ++r)
          tf[(wm + i * 16 + lq4 + r) * FST + cc] = acc[i][j][r];
      }
    __syncthreads();
    float* C = (float*)Cp_ + (size_t)bz * sCz;
    const float* R = resid + (size_t)bz * sRz;
    const int col = (tid * 4) & (BN - 1);
    const int rw0 = (tid * 4) / BN;
    constexpr int RPS = 512 * 4 / BN;  // rows per sweep
    float4 rv = *(const float4*)&rsptr[(size_t)bz * 4096 + n0 + col];
    float4 ri;
    ri.x = 1.f / rv.x; ri.y = 1.f / rv.y; ri.z = 1.f / rv.z; ri.w = 1.f / rv.w;
    #pragma unroll
    for (int s = 0; s < BM / RPS; ++s) {
      int row = s * RPS + rw0;
      float b = bias[m0 + row];
      float4 v = *(const float4*)&tf[row * FST + col];
      float4 xr = *(const float4*)(R + (size_t)(m0 + row) * ldc + n0 + col);
      v.x = v.x * ri.x + b + xr.x;
      v.y = v.y * ri.y + b + xr.y;
      v.z = v.z * ri.z + b + xr.z;
      v.w = v.w * ri.w + b + xr.w;
      *(float4*)(C + (size_t)(m0 + row) * ldc + n0 + col) = v;
    }
  }
}

extern "C" void kernel_launch(void* const* d_in, const int* in_sizes, int n_in,
                              void* d_out, int out_size, void* d_ws, size_t ws_size,
                              hipStream_t stream) {
  const float* x     = (const float*)d_in[0];
  const float* gamma = (const float*)d_in[1];
  const float* beta  = (const float*)d_in[2];
  const float* wq    = (const float*)d_in[3];
  const float* bq    = (const float*)d_in[4];
  const float* wk    = (const float*)d_in[5];
  const float* bk    = (const float*)d_in[6];
  const float* wv    = (const float*)d_in[7];
  const float* bv    = (const float*)d_in[8];
  const float* wo    = (const float*)d_in[9];
  const float* bo    = (const float*)d_in[10];
  float* out = (float*)d_out;

  const size_t BHW = (size_t)4096 * 512;       // elems per batch per tensor
  const long long SS = 16777216LL;             // 4096*4096
  u16* Wh  = (u16*)d_ws;                       // 4 x 512x512 fp16 (q,k,v,o)
  u16* xnt = Wh + (size_t)4 * 512 * 512;       // (b, s, c) — reused as V' later
  u16* qt  = xnt + 4 * BHW;                    // (b, s, c)
  u16* kt  = qt + 4 * BHW;                     // (b, s, c)
  u16* vt  = kt + 4 * BHW;                     // (b, s, c)
  u16* Sb  = vt + 4 * BHW;                     // (b, 4096, 4096) fp16 expS
  float* rowsum = (float*)(Sb + 4 * SS);       // (b, 4096) fp32
  float* rspart = rowsum + 4 * 4096;           // (b, 16, 4, 4096) fp32 slice partials
  float* gstat  = rspart + (size_t)4 * 64 * 4096;  // (b, 32, 2) fp32 mean/rstd
  u16* Vp  = xnt;                              // V' = Wo.V  (b, c, s) — alias, xnt dead after QKV

  const float scale = 0.044194173824159216f;   // 512^-0.5

  hipLaunchKernelGGL(cast4_k, dim3(1024, 4), dim3(256), 0, stream, wq, wk, wv, wo, Wh);
  hipLaunchKernelGGL(gnstat_k, dim3(32, 4), dim3(256), 0, stream, x, gstat);
  hipLaunchKernelGGL(gnapply_k, dim3(32, 4, 8), dim3(256), 0, stream, x, gamma, beta, gstat, xnt);

  // QKV: M=512 (c_out), N=4096 (s), K=512; z = proj*4 + batch; all n-major out
  hipLaunchKernelGGL((gemm_k<5, 128, 128>), dim3(32, 4, 12), dim3(256), 0, stream,
                     Wh, 512, 0LL, xnt, 512, 0LL, nullptr, 0, 0LL, 512,
                     qt, kt, vt, bq, bk, bv);

  // expS[b][i][j] = exp(q.k*scale); slice partial rowsums -> rspart ; M=N=4096, K=512
  hipLaunchKernelGGL((gemm8_k<256, 256, 0>), dim3(16, 16, 4), dim3(512), 0, stream,
                     qt, 512, (long long)BHW, kt, 512, (long long)BHW,
                     Sb, 4096, SS, 512, nullptr, nullptr, 0LL, scale, rspart);

  // rowsum[b][m] = sum over 64 slice partials
  hipLaunchKernelGGL(rsum_k, dim3(64), dim3(256), 0, stream, rspart, rowsum);

  // V'[b][co][j] = Wo[co][:].v_t[j][:] ; M=512, N=4096, K=512 (fuses final proj)
  hipLaunchKernelGGL((gemm_k<4, 128, 128>), dim3(32, 4, 4), dim3(256), 0, stream,
                     Wh + (size_t)3 * 512 * 512, 512, 0LL, vt, 512, (long long)BHW,
                     Vp, 4096, (long long)(512 * 4096), 512,
                     nullptr, nullptr, nullptr, nullptr, nullptr, nullptr);

  // out[b][co][i] = (V'[co][:].expS[i][:]) / rowsum[i] + bo[co] + x ; M=512, N=4096, K=4096
  hipLaunchKernelGGL((gemm8_k<128, 256, 1>), dim3(16, 4, 4), dim3(512), 0, stream,
                     Vp, 4096, (long long)(512 * 4096), Sb, 4096, SS,
                     out, 4096, (long long)BHW, 4096, bo, x, (long long)BHW, 0.f, rowsum);
}